// Round 2
// baseline (173.775 us; speedup 1.0000x reference)
//
#include <hip/hip_runtime.h>
#include <cmath>

#define B_LEN 8
#define S_LEN 16384
#define D_LEN 512
#define K0 32
#define K1 64
#define KTOT 96
#define ROWS 192          // output rows per b: 32 mean0, 32 var0, 64 mean1, 64 var1
#define NCHUNK 512
#define SC (S_LEN / NCHUNK)   // 32
#define UB 4                  // load batch (float4s in flight per wave)

// ws layout: p[96] floats at [0..95], q[96] floats at [96..191]
__global__ void vp_boundaries(const float* __restrict__ s0,
                              const float* __restrict__ s1,
                              float* __restrict__ pq) {
    if (threadIdx.x != 0 || blockIdx.x != 0) return;
    double e[64];
    {
        double m = -1e300;
        for (int k = 0; k < K0; ++k) m = fmax(m, (double)s0[k] * 10.0);
        double sum = 0.0;
        for (int k = 0; k < K0; ++k) { e[k] = exp((double)s0[k] * 10.0 - m); sum += e[k]; }
        double c = 0.0;
        for (int k = 0; k < K0; ++k) {
            float p = (float)(c * (double)S_LEN);
            c += e[k] / sum;
            float q = fminf((float)(c * (double)S_LEN), (float)S_LEN - 0.01f);
            pq[k] = p;
            pq[KTOT + k] = q;
        }
    }
    {
        double m = -1e300;
        for (int k = 0; k < K1; ++k) m = fmax(m, (double)s1[k] * 10.0);
        double sum = 0.0;
        for (int k = 0; k < K1; ++k) { e[k] = exp((double)s1[k] * 10.0 - m); sum += e[k]; }
        double c = 0.0;
        for (int k = 0; k < K1; ++k) {
            float p = (float)(c * (double)S_LEN);
            c += e[k] / sum;
            float q = fminf((float)(c * (double)S_LEN), (float)S_LEN - 0.01f);
            pq[K0 + k] = p;
            pq[KTOT + K0 + k] = q;
        }
    }
}

// zero d_out (out_size = 786432 floats = 196608 float4)
__global__ void vp_zero(float4* __restrict__ out) {
    const int i = blockIdx.x * blockDim.x + threadIdx.x;
    out[i] = make_float4(0.f, 0.f, 0.f, 0.f);
}

// Streaming pass: one read of x; accumulate sx (into mean slots) and sx2 (into
// var slots) of d_out via atomicAdd. d_out zeroed beforehand by vp_zero.
__global__ __launch_bounds__(128, 8) void vp_main(const float* __restrict__ x,
                                                  const float* __restrict__ pq,
                                                  float* __restrict__ out) {
    __shared__ float spq[2 * KTOT];
    for (int i = threadIdx.x; i < 2 * KTOT; i += 128) spq[i] = pq[i];
    __syncthreads();

    const int chunk = blockIdx.x;
    const int b     = blockIdx.y;
    const int d     = threadIdx.x << 2;
    const int s_begin = chunk * SC;
    const int s_end   = s_begin + SC;
    const float fsb = (float)s_begin;

    int k0 = 0; while (k0 < K0 && spq[KTOT + k0] <= fsb) ++k0;
    int k1 = 0; while (k1 < K1 && spq[KTOT + K0 + k1] <= fsb) ++k1;
    float p0 = 0.f, q0 = 0.f, p1 = 0.f, q1 = 0.f;
    if (k0 < K0) { p0 = spq[k0];      q0 = spq[KTOT + k0]; }
    if (k1 < K1) { p1 = spq[K0 + k1]; q1 = spq[KTOT + K0 + k1]; }

    float a0x=0.f,a0y=0.f,a0z=0.f,a0w=0.f, c0x=0.f,c0y=0.f,c0z=0.f,c0w=0.f;
    float a1x=0.f,a1y=0.f,a1z=0.f,a1w=0.f, c1x=0.f,c1y=0.f,c1z=0.f,c1w=0.f;

    const float* xb = x + (size_t)b * S_LEN * D_LEN + d;
    float* ob = out + (size_t)b * ROWS * D_LEN + d;

#define FLUSH(MROW, VROW, ax,ay,az,aw, cx,cy,cz,cw) do {                     \
    float* mp_ = ob + (size_t)(MROW) * D_LEN;                                \
    float* vp_ = ob + (size_t)(VROW) * D_LEN;                                \
    atomicAdd(mp_+0, ax); atomicAdd(mp_+1, ay);                              \
    atomicAdd(mp_+2, az); atomicAdd(mp_+3, aw);                              \
    atomicAdd(vp_+0, cx); atomicAdd(vp_+1, cy);                              \
    atomicAdd(vp_+2, cz); atomicAdd(vp_+3, cw);                              \
    ax=0.f;ay=0.f;az=0.f;aw=0.f;cx=0.f;cy=0.f;cz=0.f;cw=0.f; } while (0)

#define PROC(XV, S) do {                                                     \
    const float xx = (XV).x*(XV).x, xy = (XV).y*(XV).y,                      \
                xz = (XV).z*(XV).z, xw = (XV).w*(XV).w;                      \
    const float fs = (float)(S), fs1 = fs + 1.0f;                            \
    while (k0 < K0 && q0 <= fs1) {                                           \
        const float w = fmaxf(q0 - fmaxf(p0, fs), 0.f);                      \
        a0x += w*(XV).x; a0y += w*(XV).y; a0z += w*(XV).z; a0w += w*(XV).w;  \
        c0x += w*xx;     c0y += w*xy;     c0z += w*xz;     c0w += w*xw;      \
        FLUSH(k0, K0 + k0, a0x,a0y,a0z,a0w, c0x,c0y,c0z,c0w);                \
        ++k0;                                                                \
        if (k0 < K0) { p0 = spq[k0]; q0 = spq[KTOT + k0]; }                  \
    }                                                                        \
    if (k0 < K0) {                                                           \
        const float w = fmaxf(fs1 - fmaxf(p0, fs), 0.f);                     \
        a0x += w*(XV).x; a0y += w*(XV).y; a0z += w*(XV).z; a0w += w*(XV).w;  \
        c0x += w*xx;     c0y += w*xy;     c0z += w*xz;     c0w += w*xw;      \
    }                                                                        \
    while (k1 < K1 && q1 <= fs1) {                                           \
        const float w = fmaxf(q1 - fmaxf(p1, fs), 0.f);                      \
        a1x += w*(XV).x; a1y += w*(XV).y; a1z += w*(XV).z; a1w += w*(XV).w;  \
        c1x += w*xx;     c1y += w*xy;     c1z += w*xz;     c1w += w*xw;      \
        FLUSH(64 + k1, 128 + k1, a1x,a1y,a1z,a1w, c1x,c1y,c1z,c1w);          \
        ++k1;                                                                \
        if (k1 < K1) { p1 = spq[K0 + k1]; q1 = spq[KTOT + K0 + k1]; }        \
    }                                                                        \
    if (k1 < K1) {                                                           \
        const float w = fmaxf(fs1 - fmaxf(p1, fs), 0.f);                     \
        a1x += w*(XV).x; a1y += w*(XV).y; a1z += w*(XV).z; a1w += w*(XV).w;  \
        c1x += w*xx;     c1y += w*xy;     c1z += w*xz;     c1w += w*xw;      \
    } } while (0)

    for (int sb = s_begin; sb < s_end; sb += UB) {
        // issue UB loads back-to-back -> MLP=UB per wave
        const float4 xv0 = *(const float4*)(xb + (size_t)(sb + 0) * D_LEN);
        const float4 xv1 = *(const float4*)(xb + (size_t)(sb + 1) * D_LEN);
        const float4 xv2 = *(const float4*)(xb + (size_t)(sb + 2) * D_LEN);
        const float4 xv3 = *(const float4*)(xb + (size_t)(sb + 3) * D_LEN);
        PROC(xv0, sb + 0);
        PROC(xv1, sb + 1);
        PROC(xv2, sb + 2);
        PROC(xv3, sb + 3);
    }

    if (k0 < K0) FLUSH(k0, K0 + k0, a0x,a0y,a0z,a0w, c0x,c0y,c0z,c0w);
    if (k1 < K1) FLUSH(64 + k1, 128 + k1, a1x,a1y,a1z,a1w, c1x,c1y,c1z,c1w);
#undef PROC
#undef FLUSH
}

// In-place: mean slot holds sx, var slot holds sx2 -> convert to mean / std.
__global__ void vp_finalize(const float* __restrict__ pq, float* __restrict__ out) {
    const int idx = blockIdx.x * blockDim.x + threadIdx.x;
    if (idx >= B_LEN * KTOT * D_LEN) return;
    const int d = idx % D_LEN;
    const int t = idx / D_LEN;
    const int k = t % KTOT;
    const int b = t / KTOT;

    const float p = pq[k];
    const float q = pq[KTOT + k];
    const float denom = q - p;

    int meanrow, varrow;
    if (k < K0) { meanrow = k;              varrow = K0 + k;         }
    else        { meanrow = 64 + (k - K0);  varrow = 128 + (k - K0); }

    float* ob = out + (size_t)b * ROWS * D_LEN;
    const float sx  = ob[(size_t)meanrow * D_LEN + d];
    const float sx2 = ob[(size_t)varrow  * D_LEN + d];
    const float mean = sx / denom;
    const float stdv = sqrtf(fmaxf(sx2 - mean * mean * denom, 0.f) / denom);
    ob[(size_t)meanrow * D_LEN + d] = mean;
    ob[(size_t)varrow  * D_LEN + d] = stdv;
}

extern "C" void kernel_launch(void* const* d_in, const int* in_sizes, int n_in,
                              void* d_out, int out_size, void* d_ws, size_t ws_size,
                              hipStream_t stream) {
    const float* x  = (const float*)d_in[0];
    const float* s0 = (const float*)d_in[1];
    const float* s1 = (const float*)d_in[2];
    float* out = (float*)d_out;
    float* pq  = (float*)d_ws;   // 192 floats

    // zero out (786432 floats = 196608 float4; 768 blocks x 256 threads)
    vp_zero<<<768, 256, 0, stream>>>((float4*)out);
    vp_boundaries<<<1, 64, 0, stream>>>(s0, s1, pq);

    dim3 grid(NCHUNK, B_LEN);
    vp_main<<<grid, 128, 0, stream>>>(x, pq, out);

    const int total = B_LEN * KTOT * D_LEN;
    vp_finalize<<<(total + 255) / 256, 256, 0, stream>>>(pq, out);
}

// Round 3
// 82.402 us; speedup vs baseline: 2.1089x; 2.1089x over previous
//
#include <hip/hip_runtime.h>
#include <cmath>

#define B_LEN 8
#define S_LEN 16384
#define D_LEN 512
#define K0 32
#define K1 64
#define KTOT 96
#define ROWS 192          // rows per b: 32 mean0, 32 var0, 64 mean1, 64 var1
#define UB 16             // loads in flight per buffer
#define NT 256            // threads/block, 2 floats each -> 512 d

// ws layout: p[96] at [0..95], q[96] at [96..191]
__global__ void vp_boundaries(const float* __restrict__ s0,
                              const float* __restrict__ s1,
                              float* __restrict__ pq) {
    if (threadIdx.x != 0 || blockIdx.x != 0) return;
    double e[64];
    {
        double m = -1e300;
        for (int k = 0; k < K0; ++k) m = fmax(m, (double)s0[k] * 10.0);
        double sum = 0.0;
        for (int k = 0; k < K0; ++k) { e[k] = exp((double)s0[k] * 10.0 - m); sum += e[k]; }
        double c = 0.0;
        for (int k = 0; k < K0; ++k) {
            float p = (float)(c * (double)S_LEN);
            c += e[k] / sum;
            float q = fminf((float)(c * (double)S_LEN), (float)S_LEN - 0.01f);
            pq[k] = p;
            pq[KTOT + k] = q;
        }
    }
    {
        double m = -1e300;
        for (int k = 0; k < K1; ++k) m = fmax(m, (double)s1[k] * 10.0);
        double sum = 0.0;
        for (int k = 0; k < K1; ++k) { e[k] = exp((double)s1[k] * 10.0 - m); sum += e[k]; }
        double c = 0.0;
        for (int k = 0; k < K1; ++k) {
            float p = (float)(c * (double)S_LEN);
            c += e[k] / sum;
            float q = fminf((float)(c * (double)S_LEN), (float)S_LEN - 0.01f);
            pq[K0 + k] = p;
            pq[KTOT + K0 + k] = q;
        }
    }
}

// zero d_out (786432 floats = 196608 float4)
__global__ void vp_zero(float4* __restrict__ out) {
    const int i = blockIdx.x * blockDim.x + threadIdx.x;
    out[i] = make_float4(0.f, 0.f, 0.f, 0.f);
}

// One block per (set0 segment, b). Streams its s-range once. Set0 sums ->
// direct store. Set1 segments inside the range: direct store if fully
// contained, atomicAdd partials if straddling a block boundary (weights
// clipped to [P,Q) so straddler pieces partition exactly).
__global__ __launch_bounds__(NT) void vp_main(const float* __restrict__ x,
                                              const float* __restrict__ pq,
                                              float* __restrict__ out) {
    __shared__ float spq[2 * KTOT];
    for (int i = threadIdx.x; i < 2 * KTOT; i += NT) spq[i] = pq[i];
    __syncthreads();

    const int kb = blockIdx.x;   // set0 segment index
    const int b  = blockIdx.y;
    const float P = spq[kb];
    const float Q = spq[KTOT + kb];
    const int sA     = (int)P;                 // first s with weight > 0
    const int s_last = (int)ceilf(Q) - 1;      // last s with weight > 0

    // set1 segments overlapping [P,Q): k1 = first with q1 > P (it must also
    // have p1 <= P, so overlap guaranteed); k1_end = last with p1 < Q.
    int k1 = 0;
    while (k1 < K1 && spq[KTOT + K0 + k1] <= P) ++k1;
    int k1_end = k1;
    while (k1_end + 1 < K1 && spq[K0 + k1_end + 1] < Q) ++k1_end;
    float p1 = spq[K0 + k1], q1 = spq[KTOT + K0 + k1];

    const int d2 = threadIdx.x * 2;
    const float* xb = x + (size_t)b * S_LEN * D_LEN + d2;
    float* ob = out + (size_t)b * ROWS * D_LEN + d2;

    float a0x = 0.f, a0y = 0.f, c0x = 0.f, c0y = 0.f;   // set0 raw sums
    float a1x = 0.f, a1y = 0.f, c1x = 0.f, c1y = 0.f;   // current set1 seg

#define FLUSH1() do {                                                        \
    const bool direct_ = (p1 >= P) && (q1 <= Q);                             \
    float* mp_ = ob + (size_t)(64 + k1) * D_LEN;                             \
    float* vp_ = ob + (size_t)(128 + k1) * D_LEN;                            \
    if (direct_) { mp_[0] = a1x; mp_[1] = a1y; vp_[0] = c1x; vp_[1] = c1y; } \
    else { atomicAdd(mp_ + 0, a1x); atomicAdd(mp_ + 1, a1y);                 \
           atomicAdd(vp_ + 0, c1x); atomicAdd(vp_ + 1, c1y); }               \
    a1x = 0.f; a1y = 0.f; c1x = 0.f; c1y = 0.f; } while (0)

#define PROC(V, S) do {                                                      \
    const float fs = (float)(S), fs1 = fs + 1.0f;                            \
    const float xx = (V).x * (V).x, xy = (V).y * (V).y;                      \
    const float w0 = fmaxf(fminf(Q, fs1) - fmaxf(P, fs), 0.f);               \
    a0x += w0 * (V).x; a0y += w0 * (V).y; c0x += w0 * xx; c0y += w0 * xy;    \
    while (k1 <= k1_end && q1 <= fs1) {                                      \
        const float w_ = fmaxf(fminf(fminf(q1, fs1), Q)                      \
                               - fmaxf(fmaxf(p1, fs), P), 0.f);              \
        a1x += w_ * (V).x; a1y += w_ * (V).y;                                \
        c1x += w_ * xx;    c1y += w_ * xy;                                   \
        FLUSH1();                                                            \
        ++k1;                                                                \
        if (k1 <= k1_end) { p1 = spq[K0 + k1]; q1 = spq[KTOT + K0 + k1]; }   \
    }                                                                        \
    if (k1 <= k1_end) {                                                      \
        const float w_ = fmaxf(fminf(fminf(q1, fs1), Q)                      \
                               - fmaxf(fmaxf(p1, fs), P), 0.f);              \
        a1x += w_ * (V).x; a1y += w_ * (V).y;                                \
        c1x += w_ * xx;    c1y += w_ * xy;                                   \
    } } while (0)

// padded + clamped loads: s beyond s_last contribute weight 0, address clamped
#define LD(VN, SB) do { _Pragma("unroll")                                    \
    for (int i_ = 0; i_ < UB; ++i_) {                                        \
        int s_ = (SB) + i_; s_ = (s_ < S_LEN) ? s_ : (S_LEN - 1);            \
        VN[i_] = *(const float2*)(xb + (size_t)s_ * D_LEN); } } while (0)
#define PR(VN, SB) do { _Pragma("unroll")                                    \
    for (int i_ = 0; i_ < UB; ++i_) { PROC(VN[i_], (SB) + i_); } } while (0)

    float2 vA[UB], vB[UB];
    int s0 = sA;
    LD(vA, s0);
    for (; s0 <= s_last; s0 += 2 * UB) {
        LD(vB, s0 + UB);
        PR(vA, s0);
        LD(vA, s0 + 2 * UB);
        PR(vB, s0 + UB);
    }
    if (k1 <= k1_end) FLUSH1();

    // set0: this block is the unique owner -> direct raw store
    float* mp0 = ob + (size_t)kb * D_LEN;
    float* vp0 = ob + (size_t)(K0 + kb) * D_LEN;
    mp0[0] = a0x; mp0[1] = a0y; vp0[0] = c0x; vp0[1] = c0y;
#undef LD
#undef PR
#undef PROC
#undef FLUSH1
}

// In-place: mean slot holds sx, var slot holds sx2 -> convert to mean / std.
__global__ void vp_finalize(const float* __restrict__ pq, float* __restrict__ out) {
    const int idx = blockIdx.x * blockDim.x + threadIdx.x;
    if (idx >= B_LEN * KTOT * D_LEN) return;
    const int d = idx % D_LEN;
    const int t = idx / D_LEN;
    const int k = t % KTOT;
    const int b = t / KTOT;

    const float p = pq[k];
    const float q = pq[KTOT + k];
    const float denom = q - p;

    int meanrow, varrow;
    if (k < K0) { meanrow = k;              varrow = K0 + k;         }
    else        { meanrow = 64 + (k - K0);  varrow = 128 + (k - K0); }

    float* ob = out + (size_t)b * ROWS * D_LEN;
    const float sx  = ob[(size_t)meanrow * D_LEN + d];
    const float sx2 = ob[(size_t)varrow  * D_LEN + d];
    const float mean = sx / denom;
    const float stdv = sqrtf(fmaxf(sx2 - mean * mean * denom, 0.f) / denom);
    ob[(size_t)meanrow * D_LEN + d] = mean;
    ob[(size_t)varrow  * D_LEN + d] = stdv;
}

extern "C" void kernel_launch(void* const* d_in, const int* in_sizes, int n_in,
                              void* d_out, int out_size, void* d_ws, size_t ws_size,
                              hipStream_t stream) {
    const float* x  = (const float*)d_in[0];
    const float* s0 = (const float*)d_in[1];
    const float* s1 = (const float*)d_in[2];
    float* out = (float*)d_out;
    float* pq  = (float*)d_ws;   // 192 floats

    vp_zero<<<768, 256, 0, stream>>>((float4*)out);
    vp_boundaries<<<1, 64, 0, stream>>>(s0, s1, pq);

    dim3 grid(K0, B_LEN);        // one block per (set0 segment, b)
    vp_main<<<grid, NT, 0, stream>>>(x, pq, out);

    const int total = B_LEN * KTOT * D_LEN;
    vp_finalize<<<(total + 255) / 256, 256, 0, stream>>>(pq, out);
}

// Round 4
// 56.941 us; speedup vs baseline: 3.0518x; 1.4471x over previous
//
#include <hip/hip_runtime.h>
#include <cmath>

#define B_LEN 8
#define S_LEN 16384
#define D_LEN 512
#define K0 32
#define K1 64
#define KTOT 96
#define ROWS 192          // rows per b: 32 mean0, 32 var0, 64 mean1, 64 var1
#define UB 16             // loads in flight per buffer
#define NT 256            // threads/block, float2 each -> 512 d
#define SPLIT 2           // s-split per set0 segment
#define WS_OFF 256        // floats; pq occupies [0..191]

// ---- prep: block 0 computes boundaries (wave-parallel fp64); rest zero out.
__global__ __launch_bounds__(NT) void vp_prep(const float* __restrict__ s0,
                                              const float* __restrict__ s1,
                                              float* __restrict__ pq,
                                              float4* __restrict__ outv) {
    if (blockIdx.x == 0) {
        const int lane = threadIdx.x;
        if (lane < 64) {
            for (int set = 0; set < 2; ++set) {
                const int K = set ? K1 : K0;
                const int off = set ? K0 : 0;
                const float* sc = set ? s1 : s0;
                double xv = (lane < K) ? (double)sc[lane] * 10.0 : -1e300;
                double m = xv;
                for (int d = 32; d; d >>= 1) m = fmax(m, __shfl_xor(m, d, 64));
                double e = (lane < K) ? exp(xv - m) : 0.0;
                double ssum = e;
                for (int d = 32; d; d >>= 1) ssum += __shfl_xor(ssum, d, 64);
                double incl = e;
                for (int d = 1; d < 64; d <<= 1) {
                    double t = __shfl_up(incl, d, 64);
                    if (lane >= d) incl += t;
                }
                if (lane < K) {
                    const double c = incl / ssum;
                    const float p = (float)((c - e / ssum) * (double)S_LEN);
                    const float q = fminf((float)(c * (double)S_LEN),
                                          (float)S_LEN - 0.01f);
                    pq[off + lane] = p;
                    pq[KTOT + off + lane] = q;
                }
            }
        }
    } else {
        const int i = (blockIdx.x - 1) * NT + threadIdx.x;
        outv[i] = make_float4(0.f, 0.f, 0.f, 0.f);
    }
}

// ---- main: one block per (set0 seg, b, half). Running prefix sums; segment
// boundaries handled as rare events via snapshots. Set0 partials -> ws (or
// atomics if ws too small); set1 segs direct-store if block-contained, else
// atomicAdd partial (clipped to block interval).
__global__ __launch_bounds__(NT, 2) void vp_main(const float* __restrict__ x,
                                                 const float* __restrict__ pq,
                                                 float* __restrict__ out,
                                                 float* __restrict__ ws,
                                                 int use_ws) {
    const int kb = blockIdx.x;
    const int b  = blockIdx.y;
    const int h  = blockIdx.z;

    const float P0 = pq[kb], Q0 = pq[KTOT + kb];
    const int sA0 = (int)P0;
    const int sZ0 = (int)ceilf(Q0) - 1;
    const int mid = (sA0 + sZ0 + 1) >> 1;

    const float Pb = h ? (float)mid : P0;
    const float Qb = h ? Q0 : (float)mid;
    const int sA = h ? mid : sA0;
    const int sZ = h ? sZ0 : mid - 1;

    const int d2 = threadIdx.x * 2;
    float* wsl = ws + WS_OFF
               + (size_t)((kb * B_LEN + b) * SPLIT + h) * (2 * D_LEN) + d2;

    if (sZ < sA || !(Pb < Qb)) {          // empty half-interval
        if (use_ws) { wsl[0] = 0.f; wsl[1] = 0.f;
                      wsl[D_LEN] = 0.f; wsl[D_LEN + 1] = 0.f; }
        return;
    }

    // first set1 segment overlapping [Pb, Qb)
    int k1 = 0;
    while (k1 < K1 && pq[KTOT + K0 + k1] <= Pb) ++k1;
    bool act1 = (k1 < K1);
    float p1 = act1 ? pq[K0 + k1] : 0.f;
    float q1 = act1 ? pq[KTOT + K0 + k1] : 0.f;
    if (act1 && p1 >= Qb) act1 = false;
    float st1 = fmaxf(p1, Pb);
    bool pend1 = act1;                 // SS1 snapshot not yet taken
    bool dir1  = act1 && (p1 >= Pb);   // block saw the segment start
    bool ss0p  = true;                 // SS0 snapshot pending (at sA)
    bool done  = false;

    float Gx = 0.f, Gy = 0.f, G2x = 0.f, G2y = 0.f;
    float SS0ax = 0.f, SS0ay = 0.f, SS0cx = 0.f, SS0cy = 0.f;
    float SS1ax = 0.f, SS1ay = 0.f, SS1cx = 0.f, SS1cy = 0.f;

    const float* xb = x + (size_t)b * S_LEN * D_LEN + d2;
    float* obase = out + (size_t)b * ROWS * D_LEN + d2;

    auto next_evt = [&]() -> int {
        if (done) return 0x7fffffff;
        int e = sZ;
        if (ss0p && sA < e) e = sA;
        if (act1) {
            const int e1 = pend1 ? (int)st1
                                 : ((int)ceilf(fminf(q1, Qb)) - 1);
            if (e1 < e) e = e1;
        }
        return e;
    };
    int evt = next_evt();

    auto handle = [&](float vx, float vy, int s) {
        const float vx2 = vx * vx, vy2 = vy * vy;
        for (;;) {
            if (ss0p && s == sA) {
                const float w = (float)(s + 1) - Pb;
                SS0ax = Gx - w * vx;  SS0ay = Gy - w * vy;
                SS0cx = G2x - w * vx2; SS0cy = G2y - w * vy2;
                ss0p = false; continue;
            }
            if (act1 && pend1 && s == (int)st1) {
                const float w = (float)(s + 1) - st1;
                SS1ax = Gx - w * vx;  SS1ay = Gy - w * vy;
                SS1cx = G2x - w * vx2; SS1cy = G2y - w * vy2;
                pend1 = false; continue;
            }
            if (act1 && !pend1 && s == (int)ceilf(fminf(q1, Qb)) - 1) {
                const float qe = fminf(q1, Qb);
                const float w = (float)(s + 1) - qe;
                const float sax = Gx - w * vx - SS1ax;
                const float say = Gy - w * vy - SS1ay;
                const float scx = G2x - w * vx2 - SS1cx;
                const float scy = G2y - w * vy2 - SS1cy;
                float* mp = obase + (size_t)(64 + k1) * D_LEN;
                float* vp = obase + (size_t)(128 + k1) * D_LEN;
                if (dir1 && q1 <= Qb) {
                    mp[0] = sax; mp[1] = say; vp[0] = scx; vp[1] = scy;
                } else {
                    atomicAdd(mp, sax); atomicAdd(mp + 1, say);
                    atomicAdd(vp, scx); atomicAdd(vp + 1, scy);
                }
                if (q1 < Qb && k1 + 1 < K1) {
                    ++k1;
                    p1 = pq[K0 + k1]; q1 = pq[KTOT + K0 + k1];
                    if (p1 >= Qb) act1 = false;
                    else { st1 = fmaxf(p1, Pb); pend1 = true; dir1 = (p1 >= Pb); }
                } else {
                    act1 = false;
                }
                continue;
            }
            if (!done && s == sZ) {
                const float w = (float)(s + 1) - Qb;
                const float sax = Gx - w * vx - SS0ax;
                const float say = Gy - w * vy - SS0ay;
                const float scx = G2x - w * vx2 - SS0cx;
                const float scy = G2y - w * vy2 - SS0cy;
                if (use_ws) {
                    wsl[0] = sax; wsl[1] = say;
                    wsl[D_LEN] = scx; wsl[D_LEN + 1] = scy;
                } else {
                    float* mp = obase + (size_t)kb * D_LEN;
                    float* vp = obase + (size_t)(K0 + kb) * D_LEN;
                    atomicAdd(mp, sax); atomicAdd(mp + 1, say);
                    atomicAdd(vp, scx); atomicAdd(vp + 1, scy);
                }
                done = true; continue;
            }
            break;
        }
        evt = next_evt();
    };

#define ACC(V, S) do {                                                       \
    Gx += (V).x; Gy += (V).y;                                                \
    G2x = fmaf((V).x, (V).x, G2x); G2y = fmaf((V).y, (V).y, G2y);            \
    if ((S) == evt) handle((V).x, (V).y, (S)); } while (0)

#define LD(VN, SB) do { _Pragma("unroll")                                    \
    for (int i_ = 0; i_ < UB; ++i_) {                                        \
        int s_ = (SB) + i_; s_ = (s_ < S_LEN) ? s_ : (S_LEN - 1);            \
        VN[i_] = *(const float2*)(xb + (size_t)s_ * D_LEN); } } while (0)
#define PR(VN, SB) do { _Pragma("unroll")                                    \
    for (int i_ = 0; i_ < UB; ++i_) { ACC(VN[i_], (SB) + i_); } } while (0)

    float2 vA[UB], vB[UB];
    int sb = sA;
    LD(vA, sb);
    for (; sb <= sZ; sb += 2 * UB) {
        LD(vB, sb + UB);
        PR(vA, sb);
        LD(vA, sb + 2 * UB);
        PR(vB, sb + UB);
    }
#undef ACC
#undef LD
#undef PR
}

// ---- finalize: combine ws partials (set0) / read raw sums (set1), write
// mean and std in place.
__global__ __launch_bounds__(256) void vp_finalize(const float* __restrict__ pq,
                                                   float* __restrict__ out,
                                                   const float* __restrict__ ws,
                                                   int use_ws) {
    const int idx = blockIdx.x * blockDim.x + threadIdx.x;
    if (idx >= B_LEN * KTOT * D_LEN) return;
    const int d = idx % D_LEN;
    const int t = idx / D_LEN;
    const int k = t % KTOT;
    const int b = t / KTOT;

    const float p = pq[k];
    const float q = pq[KTOT + k];
    const float denom = q - p;

    int meanrow, varrow;
    float sx, sx2;
    float* ob = out + (size_t)b * ROWS * D_LEN;
    if (k < K0) {
        meanrow = k; varrow = K0 + k;
        if (use_ws) {
            const float* w0 = ws + WS_OFF
                            + (size_t)((k * B_LEN + b) * SPLIT) * (2 * D_LEN);
            const float* w1 = w0 + 2 * D_LEN;
            sx  = w0[d] + w1[d];
            sx2 = w0[D_LEN + d] + w1[D_LEN + d];
        } else {
            sx  = ob[(size_t)meanrow * D_LEN + d];
            sx2 = ob[(size_t)varrow  * D_LEN + d];
        }
    } else {
        meanrow = 64 + (k - K0); varrow = 128 + (k - K0);
        sx  = ob[(size_t)meanrow * D_LEN + d];
        sx2 = ob[(size_t)varrow  * D_LEN + d];
    }

    const float mean = sx / denom;
    const float stdv = sqrtf(fmaxf(sx2 - mean * mean * denom, 0.f) / denom);
    ob[(size_t)meanrow * D_LEN + d] = mean;
    ob[(size_t)varrow  * D_LEN + d] = stdv;
}

extern "C" void kernel_launch(void* const* d_in, const int* in_sizes, int n_in,
                              void* d_out, int out_size, void* d_ws, size_t ws_size,
                              hipStream_t stream) {
    const float* x  = (const float*)d_in[0];
    const float* s0 = (const float*)d_in[1];
    const float* s1 = (const float*)d_in[2];
    float* out = (float*)d_out;
    float* ws  = (float*)d_ws;

    const size_t ws_need = (size_t)(WS_OFF + K0 * B_LEN * SPLIT * 2 * D_LEN)
                         * sizeof(float);
    const int use_ws = (ws_size >= ws_need) ? 1 : 0;

    // prep: 1 boundary block + 768 zero blocks (786432 floats / 4 / 256)
    vp_prep<<<1 + 768, NT, 0, stream>>>(s0, s1, ws, (float4*)out);

    dim3 grid(K0, B_LEN, SPLIT);
    vp_main<<<grid, NT, 0, stream>>>(x, ws, out, ws, use_ws);

    const int total = B_LEN * KTOT * D_LEN;
    vp_finalize<<<(total + 255) / 256, 256, 0, stream>>>(ws, out, ws, use_ws);
}